// Round 7
// baseline (261.851 us; speedup 1.0000x reference)
//
#include <hip/hip_runtime.h>

#define BB 16
#define NN 50
#define HH 128
#define VV 40000
#define VO 39999

typedef unsigned short u16;
typedef unsigned int u32;
typedef __attribute__((ext_vector_type(8))) short short8;
typedef __attribute__((ext_vector_type(4))) float f32x4;

// ---- workspace layout (float offsets) ----
#define OFF_HID    0          // 800*128
#define OFF_HID2   102400     // 800*128 (GRU double buffer; reused as Q2 after GRU)
#define OFF_Q2     102400
#define OFF_Q1     204800     //   16*128
#define OFF_HT     206848     //   16*128
#define OFF_QTBF   307200     // qt fragments: per b: 4tile x 4kc x 512 u16 = 16 KB
#define OFF_LEN    411648     // 16 ints
#define OFF_WTWOT  591888     // 128*128 k-major
#define OFF_WTT    608272
#define OFF_WONET  624656
#define OFF_WTRT   641040     // 256*128  -> ends 673808

__device__ __forceinline__ float sigm(float x){ return 1.0f/(1.0f+__expf(-x)); }
__device__ __forceinline__ float b2f(u16 u){
  union { u32 i; float f; } c; c.i = ((u32)u) << 16; return c.f;
}
__device__ __forceinline__ u16 f2b(float f){
  union { float f; u32 i; } c; c.f = f;
  u32 u = c.i;
  return (u16)((u + 0x7fffu + ((u >> 16) & 1u)) >> 16);
}
__device__ __forceinline__ int frag_idx(int b, int n, int k){
  int tile = n>>4, vlo = n&15, kc = k>>5, quad = (k>>3)&3, j = k&7;
  return (((b*4+tile)*4+kc)<<9) + ((quad<<4)+vlo)*8 + j;
}

// ---- merged: embedding gather + transpose post-phase weights to k-major ----
__global__ void k_pre(const int* __restrict__ items, const float* __restrict__ emb,
                      const float* __restrict__ W_two, const float* __restrict__ W_t,
                      const float* __restrict__ W_one, const float* __restrict__ W_tr,
                      float* __restrict__ ws){
  int idx = blockIdx.x*256 + threadIdx.x;     // grid covers exactly 184320
  if (idx < 102400){
    int r = idx >> 7, h = idx & 127;
    ws[OFF_HID + idx] = emb[items[r]*128 + h];
  } else if (idx < 118784){
    int i = idx-102400; int k=i>>7, h=i&127;
    ws[OFF_WTWOT + i] = W_two[h*128 + k];
  } else if (idx < 135168){
    int i = idx-118784; int k=i>>7, h=i&127;
    ws[OFF_WTT + i] = W_t[h*128 + k];
  } else if (idx < 151552){
    int i = idx-135168; int k=i>>7, h=i&127;
    ws[OFF_WONET + i] = W_one[h*128 + k];
  } else if (idx < 184320){
    int i = idx-151552; int k=i>>7, h=i&127;   // k<256
    ws[OFF_WTRT + i] = W_tr[h*256 + k];
  }
}

// ---- fused GNN step v2: 2 rows/block, grid (25,16); weights read row-major float4 ----
// per block (tile,b): hA = A_rows@H_b ; inp = hA@W^T + rowsum(A)*b_e + b_ah ; GRU gates
__global__ void __launch_bounds__(384) k_step(const float* __restrict__ A,
                       const float* __restrict__ w_ih, const float* __restrict__ w_hh,
                       const float* __restrict__ W_ein, const float* __restrict__ W_eout,
                       const float* __restrict__ b_ein, const float* __restrict__ b_eout,
                       const float* __restrict__ b_iah, const float* __restrict__ b_oah,
                       const float* __restrict__ b_ih, const float* __restrict__ b_hh,
                       float* __restrict__ ws, int srcOff, int dstOff){
  __shared__ float hall[50][128];    // 25.6 KB
  __shared__ float arow[2][104];
  __shared__ float hAl[2][256];      // [r][k<128]=A_in@H, [r][128+k]=A_out@H
  __shared__ float sAl[2][2];
  __shared__ float inp[2][256];
  __shared__ float gil[2][384];
  __shared__ float ghl[2][384];      // total ~36.6 KB
  int t = threadIdx.x;
  int tile = blockIdx.x, b = blockIdx.y;
  int n0 = tile*2;
  const float* hsrc = ws + srcOff + b*6400;
  for (int o=t; o<1600; o+=384) ((float4*)hall)[o] = ((const float4*)hsrc)[o];
  for (int o=t; o<208; o+=384){
    int r=o/104, c=o-r*104;
    arow[r][c] = (c<100) ? A[(size_t)(b*NN+n0+r)*100 + c] : 0.0f;
  }
  __syncthreads();
  // hA[r][kk]: kk<128 from A cols 0..49 (in), kk>=128 from cols 50..99 (out)
  for (int o=t; o<512; o+=384){
    int r = o>>8, kk = o&255;
    int k = kk & 127;
    const float* ar = &arow[r][(kk>>7)*50];
    float acc = 0.0f;
    #pragma unroll 5
    for (int m=0;m<50;m++) acc += ar[m]*hall[m][k];
    hAl[r][kk] = acc;
  }
  if (t < 4){
    int r = t>>1, half = t&1;
    const float* ar = &arow[r][half*50];
    float s = 0.0f;
    for (int m=0;m<50;m++) s += ar[m];
    sAl[r][half] = s;
  }
  __syncthreads();
  // inp[r][c8]: weight row (c-major original layout) via float4
  for (int o=t; o<512; o+=384){
    int r = o>>8, c8 = o&255;
    int in_half = (c8 < 128);
    int c = c8 & 127;
    const float* wrow = (in_half ? W_ein : W_eout) + c*128;
    const float* hv = &hAl[r][in_half ? 0 : 128];
    float acc = in_half ? (b_iah[c] + sAl[r][0]*b_ein[c])
                        : (b_oah[c] + sAl[r][1]*b_eout[c]);
    #pragma unroll 8
    for (int k=0;k<128;k+=4){
      float4 w4 = *(const float4*)(wrow + k);
      float4 h4 = *(const float4*)(hv + k);
      acc += h4.x*w4.x + h4.y*w4.y + h4.z*w4.z + h4.w*w4.w;
    }
    inp[r][c8] = acc;
  }
  __syncthreads();
  // gates: thread j owns w_ih/w_hh row j (contiguous, float4); LDS reads broadcast
  {
    int j = t;
    float gi0=b_ih[j], gi1=gi0, gh0=b_hh[j], gh1=gh0;
    const float* wi = w_ih + j*256;
    const float* wh = w_hh + j*128;
    #pragma unroll 8
    for (int k=0;k<256;k+=4){
      float4 w4 = *(const float4*)(wi + k);
      float4 i0 = *(const float4*)(&inp[0][k]);
      float4 i1 = *(const float4*)(&inp[1][k]);
      gi0 += i0.x*w4.x + i0.y*w4.y + i0.z*w4.z + i0.w*w4.w;
      gi1 += i1.x*w4.x + i1.y*w4.y + i1.z*w4.z + i1.w*w4.w;
    }
    #pragma unroll 8
    for (int k=0;k<128;k+=4){
      float4 w4 = *(const float4*)(wh + k);
      float4 h0 = *(const float4*)(&hall[n0][k]);
      float4 h1 = *(const float4*)(&hall[n0+1][k]);
      gh0 += h0.x*w4.x + h0.y*w4.y + h0.z*w4.z + h0.w*w4.w;
      gh1 += h1.x*w4.x + h1.y*w4.y + h1.z*w4.z + h1.w*w4.w;
    }
    gil[0][j]=gi0; gil[1][j]=gi1; ghl[0][j]=gh0; ghl[1][j]=gh1;
  }
  __syncthreads();
  if (t < 256){
    int r=t>>7, h=t&127, row=n0+r;
    float ir_=gil[r][h], ii=gil[r][128+h], inw=gil[r][256+h];
    float hr_=ghl[r][h], hi2=ghl[r][128+h], hn=ghl[r][256+h];
    float rg=sigm(ir_+hr_), ig=sigm(ii+hi2), ng=tanhf(inw+rg*hn);
    float hv=hall[row][h];
    ws[dstOff + (b*NN+row)*128 + h] = ng + ig*(hv-ng);
  }
}

// ---- merged post-GRU: q2 (0..99) | qt->frags (100..199) | pad frags (200..247) | q1/ht/len (248..263) ----
__global__ void __launch_bounds__(256) k_post(const int* __restrict__ mask,
                      const float* __restrict__ b_two, const float* __restrict__ b_one,
                      float* __restrict__ ws){
  int bx = blockIdx.x, t = threadIdx.x;
  u16* qtbf = (u16*)(ws + OFF_QTBF);
  if (bx < 200){
    bool isq2 = bx < 100;
    int r0 = (isq2 ? bx : bx-100) * 8;
    __shared__ float hl[1024];
    for (int i=0;i<4;i++) hl[t+i*256] = ws[OFF_HID + r0*128 + t + i*256];
    __syncthreads();
    int h = t & 127, g = t >> 7;
    const float* wT = ws + (isq2 ? OFF_WTWOT : OFF_WTT);
    float binit = isq2 ? b_two[h] : 0.0f;
    float acc[4];
    #pragma unroll
    for (int r=0;r<4;r++) acc[r] = binit;
    for (int k4=0;k4<32;k4++){
      int k = k4*4;
      float w0 = wT[(k+0)*128+h], w1 = wT[(k+1)*128+h];
      float w2 = wT[(k+2)*128+h], w3 = wT[(k+3)*128+h];
      #pragma unroll
      for (int r=0;r<4;r++){
        float4 hv = *(const float4*)(hl + (g*4+r)*128 + k);
        acc[r] += hv.x*w0 + hv.y*w1 + hv.z*w2 + hv.w*w3;
      }
    }
    #pragma unroll
    for (int r=0;r<4;r++){
      int row = r0 + g*4 + r;
      if (isq2) ws[OFF_Q2 + row*128 + h] = acc[r];
      else {
        float val = mask[row] ? acc[r] : 0.0f;
        int b = row/NN, n = row - b*NN;
        qtbf[frag_idx(b, n, h)] = f2b(val);
      }
    }
  } else if (bx < 248){
    int i = (bx-200)*256 + t;
    #pragma unroll
    for (int kk=0;kk<2;kk++){
      int e = i*2 + kk;
      int b = e/1536, rem = e - b*1536;
      int kc = rem/384, rem2 = rem - kc*384;
      int quad = rem2/96, vv = rem2 - quad*96;
      int vlo = 4 + vv/8, j = vv & 7;
      qtbf[(((b*4+3)*4+kc)<<9) + ((quad<<4)+vlo)*8 + j] = 0;
    }
  } else {
    __shared__ float htl[128];
    int b = bx - 248;
    if (t < 128){
      int len = 0;
      for (int n=0;n<NN;n++) len += mask[b*NN+n];
      if (len<1) len=1; if (len>NN) len=NN;
      float ht = ws[OFF_HID + (b*NN + len-1)*128 + t];
      ws[OFF_HT + b*128 + t] = ht;
      htl[t] = ht;
      if (t==0) ((int*)(ws+OFF_LEN))[b] = len;
    }
    __syncthreads();
    if (t < 128){
      const float* w1T = ws + OFF_WONET;
      float q1 = b_one[t];
      for (int k=0;k<128;k+=4){
        float4 h4 = *(const float4*)(htl + k);
        q1 += h4.x*w1T[(k+0)*128+t] + h4.y*w1T[(k+1)*128+t]
            + h4.z*w1T[(k+2)*128+t] + h4.w*w1T[(k+3)*128+t];
      }
      ws[OFF_Q1 + b*128 + t] = q1;
    }
  }
}

// ---- attention: parallel logits + wave softmax + a + af; af -> frag rows 50/51 ----
__global__ void __launch_bounds__(256) k_attn2(const float* __restrict__ w_three,
                        const float* __restrict__ b_tr, float* __restrict__ ws){
  __shared__ float q2l[NN*129];
  __shared__ float q1l[128], w3l[128], htl[128], al[128], pt2[128], alg[64];
  int t = threadIdx.x;   // 256
  int b = blockIdx.x;
  for (int o=t;o<6400;o+=256){ int n=o>>7, h=o&127; q2l[n*129+h] = ws[OFF_Q2 + b*6400 + o]; }
  if (t < 128){
    q1l[t] = ws[OFF_Q1 + b*128 + t];
    w3l[t] = w_three[t];
    htl[t] = ws[OFF_HT + b*128 + t];
  }
  int len = ((const int*)(ws+OFF_LEN))[b];
  __syncthreads();
  // alpha logits: 4 lanes per n, 32 h each
  if (t < 200){
    int n = t>>2, part = t&3;
    if (n < len){
      const float* qr  = q2l + n*129 + part*32;
      const float* q1p = q1l + part*32;
      const float* w3p = w3l + part*32;
      float s = 0.0f;
      for (int h=0;h<32;h++) s += w3p[h]*sigm(q1p[h]+qr[h]);
      s += __shfl_xor(s,1); s += __shfl_xor(s,2);
      if (part==0) alg[n] = s;
    }
  }
  __syncthreads();
  // parallel softmax over n (wave 0)
  if (t < 64){
    float v = (t<len) ? alg[t] : -1e30f;
    float m = v;
    m = fmaxf(m, __shfl_xor(m,1));  m = fmaxf(m, __shfl_xor(m,2));
    m = fmaxf(m, __shfl_xor(m,4));  m = fmaxf(m, __shfl_xor(m,8));
    m = fmaxf(m, __shfl_xor(m,16)); m = fmaxf(m, __shfl_xor(m,32));
    float e = (t<len) ? __expf(v - m) : 0.0f;
    float ss = e;
    ss += __shfl_xor(ss,1);  ss += __shfl_xor(ss,2);
    ss += __shfl_xor(ss,4);  ss += __shfl_xor(ss,8);
    ss += __shfl_xor(ss,16); ss += __shfl_xor(ss,32);
    float inv = 1.0f/ss;
    if (t<len) alg[t] = e*inv;
  }
  __syncthreads();
  if (t < 128){
    const float* hid = ws + OFF_HID + b*6400;
    float a = 0.0f;
    for (int n=0;n<len;n++) a += alg[n]*hid[n*128+t];
    al[t] = a;
  }
  __syncthreads();
  float p1 = 0.0f;
  if (t < 256){
    int g2 = t>>7, h = t&127;
    const float* wtr = ws + OFF_WTRT + g2*128*128;
    const float* src = g2 ? htl : al;
    float p = 0.0f;
    for (int k=0;k<128;k++) p += src[k]*wtr[k*128+h];
    if (g2) pt2[h] = p; else p1 = p;
  }
  __syncthreads();
  if (t < 128){
    float af = b_tr[t] + p1 + pt2[t];
    u16 hi = f2b(af);
    u16 lo = f2b(af - b2f(hi));
    u16* qtbf = (u16*)(ws + OFF_QTBF);
    qtbf[frag_idx(b, 50, t)] = hi;
    qtbf[frag_idx(b, 51, t)] = lo;
  }
}

// ---- MFMA scores: LDS-staged fragments; grid (4,625): x=b-group (L2 emb reuse), y=v-chunk ----
__global__ void __launch_bounds__(256) k_scores(const float* __restrict__ emb,
                                                const float* __restrict__ ws,
                                                float* __restrict__ out){
  __shared__ u16 qlds[8192];   // 16 KB = one b's fragment block
  int tid = threadIdx.x;
  int lane = tid & 63, wave = tid >> 6;
  int quad = lane >> 4, vlo = lane & 15;
  int v = blockIdx.y*64 + wave*16 + vlo;
  int vc = (v < VO) ? v : (VO-1);
  const float* erow = emb + (size_t)(vc+1)*128;
  short8 bfr[4];
  #pragma unroll
  for (int kc=0;kc<4;kc++){
    const float4* p = (const float4*)(erow + kc*32 + quad*8);
    float4 x = p[0], y = p[1];
    union { short8 s; u32 w[4]; } u;
    u.w[0] = (u32)f2b(x.x) | ((u32)f2b(x.y)<<16);
    u.w[1] = (u32)f2b(x.z) | ((u32)f2b(x.w)<<16);
    u.w[2] = (u32)f2b(y.x) | ((u32)f2b(y.y)<<16);
    u.w[3] = (u32)f2b(y.z) | ((u32)f2b(y.w)<<16);
    bfr[kc] = u.s;
  }
  const u16* qtf = (const u16*)(ws + OFF_QTBF);
  const int* slen = (const int*)(ws + OFF_LEN);
  int b0 = blockIdx.x*4;
  for (int bi=0;bi<4;bi++){
    int b = b0 + bi;
    __syncthreads();
    {
      const uint4* src = (const uint4*)qtf + (size_t)b*1024;
      uint4* dst = (uint4*)qlds;
      #pragma unroll
      for (int r=0;r<4;r++) dst[tid + r*256] = src[tid + r*256];
    }
    __syncthreads();
    int len = slen[b];
    f32x4 acc0={0.f,0.f,0.f,0.f}, acc1=acc0, acc2=acc0, acc3=acc0;
    #pragma unroll
    for (int kc=0;kc<4;kc++){
      const u16* base = qlds + kc*512 + lane*8;   // tile stride 2048 u16
      short8 a0 = *(const short8*)(base + 0*2048);
      short8 a1 = *(const short8*)(base + 1*2048);
      short8 a2 = *(const short8*)(base + 2*2048);
      short8 a3 = *(const short8*)(base + 3*2048);
      acc0 = __builtin_amdgcn_mfma_f32_16x16x32_bf16(a0, bfr[kc], acc0, 0,0,0);
      acc1 = __builtin_amdgcn_mfma_f32_16x16x32_bf16(a1, bfr[kc], acc1, 0,0,0);
      acc2 = __builtin_amdgcn_mfma_f32_16x16x32_bf16(a2, bfr[kc], acc2, 0,0,0);
      acc3 = __builtin_amdgcn_mfma_f32_16x16x32_bf16(a3, bfr[kc], acc3, 0,0,0);
    }
    int nb = quad*4;
    float ss=0.f, nm=0.f;
    #pragma unroll
    for (int r=0;r<4;r++){
      { int n=nb+r;    if(n<len){ float e=__expf(acc0[r]); ss+=e; nm+=e*acc0[r]; } }
      { int n=nb+r+16; if(n<len){ float e=__expf(acc1[r]); ss+=e; nm+=e*acc1[r]; } }
      { int n=nb+r+32; if(n<len){ float e=__expf(acc2[r]); ss+=e; nm+=e*acc2[r]; } }
      { int n=nb+r+48; if(n<len){ float e=__expf(acc3[r]); ss+=e; nm+=e*acc3[r]; } }
    }
    ss += __shfl_xor(ss,16); ss += __shfl_xor(ss,32);
    nm += __shfl_xor(nm,16); nm += __shfl_xor(nm,32);
    if (quad==0 && v < VO){
      float pa = acc3[2] + acc3[3];   // n=50 (af_hi) + n=51 (af_lo)
      out[(size_t)b*VO + v] = nm/ss + pa;
    }
  }
}

extern "C" void kernel_launch(void* const* d_in, const int* in_sizes, int n_in,
                              void* d_out, int out_size, void* d_ws, size_t ws_size,
                              hipStream_t stream){
  const int*   items  = (const int*)d_in[0];
  const float* A      = (const float*)d_in[1];
  const int*   mask   = (const int*)d_in[2];
  const float* emb    = (const float*)d_in[3];
  const float* w_ih   = (const float*)d_in[4];
  const float* w_hh   = (const float*)d_in[5];
  const float* b_ih   = (const float*)d_in[6];
  const float* b_hh   = (const float*)d_in[7];
  const float* b_iah  = (const float*)d_in[8];
  const float* b_oah  = (const float*)d_in[9];
  const float* W_ein  = (const float*)d_in[10];
  const float* b_ein  = (const float*)d_in[11];
  const float* W_eout = (const float*)d_in[12];
  const float* b_eout = (const float*)d_in[13];
  const float* W_one  = (const float*)d_in[14];
  const float* b_one  = (const float*)d_in[15];
  const float* W_two  = (const float*)d_in[16];
  const float* b_two  = (const float*)d_in[17];
  const float* w_three= (const float*)d_in[18];
  const float* W_tr   = (const float*)d_in[19];
  const float* b_tr   = (const float*)d_in[20];
  const float* W_t    = (const float*)d_in[21];
  float* ws  = (float*)d_ws;
  float* out = (float*)d_out;

  k_pre<<<720,256,0,stream>>>(items,emb,W_two,W_t,W_one,W_tr,ws);
  k_step<<<dim3(25,16),384,0,stream>>>(A,w_ih,w_hh,W_ein,W_eout,b_ein,b_eout,b_iah,b_oah,b_ih,b_hh,ws,OFF_HID,OFF_HID2);
  k_step<<<dim3(25,16),384,0,stream>>>(A,w_ih,w_hh,W_ein,W_eout,b_ein,b_eout,b_iah,b_oah,b_ih,b_hh,ws,OFF_HID2,OFF_HID);
  k_post<<<264,256,0,stream>>>(mask,b_two,b_one,ws);
  k_attn2<<<16,256,0,stream>>>(w_three,b_tr,ws);
  k_scores<<<dim3(4,625),256,0,stream>>>(emb,ws,out);
}

// Round 8
// 218.929 us; speedup vs baseline: 1.1961x; 1.1961x over previous
//
#include <hip/hip_runtime.h>

#define BB 16
#define NN 50
#define HH 128
#define VV 40000
#define VO 39999

typedef unsigned short u16;
typedef unsigned int u32;
typedef __attribute__((ext_vector_type(8))) short short8;
typedef __attribute__((ext_vector_type(4))) float f32x4;

// ---- workspace layout (float offsets) ---- high-water 667216 < 673808 (prior session)
#define OFF_HID    0          // 800*128
#define OFF_HID2   102400     // 800*128 (GRU double buffer; reused as Q2 after GRU)
#define OFF_Q2     102400
#define OFF_Q1     204800     // 16*128
#define OFF_HT     206848     // 16*128
#define OFF_WTWOT  208896     // 128*128 k-major
#define OFF_WTT    225280
#define OFF_WONET  241664
#define OFF_WTRT   258048     // 256*128 -> 290816
#define OFF_WEINT  290816     // 128*128 k-major -> 307200
#define OFF_QTBF   307200     // qt frags: 16 b x 8192 u16 = 65536 f32 -> 372736
#define OFF_WEOUTT 372736     // 128*128 k-major -> 389120
#define OFF_LEN    411648     // 16 ints
#define OFF_HA     411664     // 800*256 fp32 (GRU transient) -> 616464
#define OFF_WHHT   616464     // 128*384 k-major -> 665616
#define OFF_HASUM  665616     // 800*2 -> 667216

__device__ __forceinline__ float sigm(float x){ return 1.0f/(1.0f+__expf(-x)); }
__device__ __forceinline__ float b2f(u16 u){
  union { u32 i; float f; } c; c.i = ((u32)u) << 16; return c.f;
}
__device__ __forceinline__ u16 f2b(float f){
  union { float f; u32 i; } c; c.f = f;
  u32 u = c.i;
  return (u16)((u + 0x7fffu + ((u >> 16) & 1u)) >> 16);
}
__device__ __forceinline__ int frag_idx(int b, int n, int k){
  int tile = n>>4, vlo = n&15, kc = k>>5, quad = (k>>3)&3, j = k&7;
  return (((b*4+tile)*4+kc)<<9) + ((quad<<4)+vlo)*8 + j;
}

// ---- merged: embedding gather + k-major transposes (post weights + WeT/WhhT) ----
__global__ void k_pre(const int* __restrict__ items, const float* __restrict__ emb,
                      const float* __restrict__ W_two, const float* __restrict__ W_t,
                      const float* __restrict__ W_one, const float* __restrict__ W_tr,
                      const float* __restrict__ W_ein, const float* __restrict__ W_eout,
                      const float* __restrict__ w_hh, float* __restrict__ ws){
  int idx = blockIdx.x*256 + threadIdx.x;     // grid covers exactly 266240
  if (idx < 102400){
    int r = idx >> 7, h = idx & 127;
    ws[OFF_HID + idx] = emb[items[r]*128 + h];
  } else if (idx < 118784){
    int i = idx-102400; int k=i>>7, h=i&127;
    ws[OFF_WTWOT + i] = W_two[h*128 + k];
  } else if (idx < 135168){
    int i = idx-118784; int k=i>>7, h=i&127;
    ws[OFF_WTT + i] = W_t[h*128 + k];
  } else if (idx < 151552){
    int i = idx-135168; int k=i>>7, h=i&127;
    ws[OFF_WONET + i] = W_one[h*128 + k];
  } else if (idx < 184320){
    int i = idx-151552; int k=i>>7, h=i&127;   // k<256
    ws[OFF_WTRT + i] = W_tr[h*256 + k];
  } else if (idx < 200704){
    int i = idx-184320; int k=i>>7, h=i&127;
    ws[OFF_WEINT + i] = W_ein[h*128 + k];
  } else if (idx < 217088){
    int i = idx-200704; int k=i>>7, h=i&127;
    ws[OFF_WEOUTT + i] = W_eout[h*128 + k];
  } else if (idx < 266240){
    int i = idx-217088; int k=i/384, j=i-k*384;   // k<128, j<384
    ws[OFF_WHHT + i] = w_hh[j*128 + k];
  }
}

// ---- hA = A@H (reassoc) + rowsums; grid (13,16) x 384 ----
__global__ void __launch_bounds__(384) k_ha(const float* __restrict__ A,
                       float* __restrict__ ws, int srcOff){
  __shared__ float hall[50][128];    // 25.6 KB
  __shared__ float arow[4][104];
  int t = threadIdx.x;
  int tile = blockIdx.x, b = blockIdx.y;
  int n0 = tile*4;
  const float* hsrc = ws + srcOff + b*6400;
  for (int o=t; o<1600; o+=384) ((float4*)hall)[o] = ((const float4*)hsrc)[o];
  for (int o=t; o<416; o+=384){
    int r=o/104, c=o-r*104;
    arow[r][c] = (c<100 && n0+r<NN) ? A[(size_t)(b*NN+n0+r)*100 + c] : 0.0f;
  }
  __syncthreads();
  for (int o=t; o<1024; o+=384){
    int r = o>>8, kk = o&255;
    int row = n0 + r;
    if (row < NN){
      int k = kk & 127;
      const float* ar = &arow[r][(kk>>7)*50];
      float acc = 0.0f;
      #pragma unroll 5
      for (int m=0;m<50;m++) acc += ar[m]*hall[m][k];
      ws[OFF_HA + (size_t)(b*NN+row)*256 + kk] = acc;
    }
  }
  if (t < 8){
    int r = t>>1, half = t&1;
    if (n0+r < NN){
      const float* ar = &arow[r][half*50];
      float s = 0.0f;
      for (int m=0;m<50;m++) s += ar[m];
      ws[OFF_HASUM + (b*NN+n0+r)*2 + half] = s;
    }
  }
}

// ---- gates: 4 global rows/block, grid 200 x 512; gi via LDS-staged w_ih chunks ----
__global__ void __launch_bounds__(512) k_gates(const float* __restrict__ w_ih,
                       const float* __restrict__ b_ein, const float* __restrict__ b_eout,
                       const float* __restrict__ b_iah, const float* __restrict__ b_oah,
                       const float* __restrict__ b_ih, const float* __restrict__ b_hh,
                       float* __restrict__ ws, int srcOff, int dstOff){
  __shared__ float h4[4][128];       // 2 KB
  __shared__ float ha4[4][256];      // 4 KB
  __shared__ float sa4[4][2];
  __shared__ float inp4[4][256];     // 4 KB
  __shared__ float gil[4][384];      // 6 KB
  __shared__ float ghl[4][384];      // 6 KB
  __shared__ float wtile[16][384];   // 24 KB  -> total ~47 KB
  int t = threadIdx.x;
  int g0 = blockIdx.x*4;             // global rows g0..g0+3 (0..799)
  h4[t>>7][t&127] = ws[srcOff + g0*128 + t];
  ha4[t>>8][t&255] = ws[OFF_HA + g0*256 + t];
  { int o2 = t+512; ha4[o2>>8][o2&255] = ws[OFF_HA + g0*256 + o2]; }
  if (t < 8) sa4[t>>1][t&1] = ws[OFF_HASUM + g0*2 + t];
  __syncthreads();
  // ---- inp = hA@WeT + bias folds (K=128, k-major coalesced scalar) ----
  {
    int c8 = t & 255, rb = t >> 8;   // rb in {0,1}: rows rb and rb+2 share weight column
    int in_half = (c8 < 128) ? 1 : 0;
    int c = c8 & 127;
    const float* wT = ws + (in_half ? OFF_WEINT : OFF_WEOUTT) + c;
    const float* haA = &ha4[rb][in_half ? 0 : 128];
    const float* haB = &ha4[rb+2][in_half ? 0 : 128];
    float a0 = in_half ? (b_iah[c] + sa4[rb  ][0]*b_ein[c]) : (b_oah[c] + sa4[rb  ][1]*b_eout[c]);
    float a1 = in_half ? (b_iah[c] + sa4[rb+2][0]*b_ein[c]) : (b_oah[c] + sa4[rb+2][1]*b_eout[c]);
    for (int k=0;k<128;k+=4){
      float w0=wT[(k+0)*128], w1=wT[(k+1)*128], w2=wT[(k+2)*128], w3=wT[(k+3)*128];
      float4 hA = *(const float4*)(haA + k);
      float4 hB = *(const float4*)(haB + k);
      a0 += hA.x*w0 + hA.y*w1 + hA.z*w2 + hA.w*w3;
      a1 += hB.x*w0 + hB.y*w1 + hB.z*w2 + hB.w*w3;
    }
    inp4[rb][c8] = a0;
    inp4[rb+2][c8] = a1;
  }
  __syncthreads();
  // ---- gi = inp@w_ih^T (K=256): 16-wide K-chunks, w_ih coop-staged+transposed to LDS ----
  int j = t;
  float gacc0=0,gacc1=0,gacc2=0,gacc3=0;
  if (j < 384){ float bi = b_ih[j]; gacc0=gacc1=gacc2=gacc3=bi; }
  for (int k0=0;k0<256;k0+=16){
    #pragma unroll
    for (int q=0;q<3;q++){
      int u = t + q*512;               // 1536 float4 loads, coalesced 64B granules
      int row = u>>2, seg = u&3;
      float4 v = *(const float4*)(w_ih + row*256 + k0 + seg*4);
      int kb = seg*4;
      wtile[kb+0][row]=v.x; wtile[kb+1][row]=v.y; wtile[kb+2][row]=v.z; wtile[kb+3][row]=v.w;
    }
    __syncthreads();
    if (j < 384){
      #pragma unroll
      for (int kk=0;kk<16;kk++){
        float w = wtile[kk][j];
        gacc0 += w*inp4[0][k0+kk];
        gacc1 += w*inp4[1][k0+kk];
        gacc2 += w*inp4[2][k0+kk];
        gacc3 += w*inp4[3][k0+kk];
      }
    }
    __syncthreads();
  }
  if (j < 384){ gil[0][j]=gacc0; gil[1][j]=gacc1; gil[2][j]=gacc2; gil[3][j]=gacc3; }
  // ---- gh = H@w_hh^T (K=128, k-major coalesced scalar) ----
  if (j < 384){
    float bh = b_hh[j];
    float q0=bh,q1=bh,q2=bh,q3=bh;
    const float* wT = ws + OFF_WHHT + j;
    for (int k=0;k<128;k+=4){
      float w0=wT[(k+0)*384], w1=wT[(k+1)*384], w2=wT[(k+2)*384], w3=wT[(k+3)*384];
      float4 v0 = *(const float4*)(&h4[0][k]);
      float4 v1 = *(const float4*)(&h4[1][k]);
      float4 v2 = *(const float4*)(&h4[2][k]);
      float4 v3 = *(const float4*)(&h4[3][k]);
      q0 += v0.x*w0 + v0.y*w1 + v0.z*w2 + v0.w*w3;
      q1 += v1.x*w0 + v1.y*w1 + v1.z*w2 + v1.w*w3;
      q2 += v2.x*w0 + v2.y*w1 + v2.z*w2 + v2.w*w3;
      q3 += v3.x*w0 + v3.y*w1 + v3.z*w2 + v3.w*w3;
    }
    ghl[0][j]=q0; ghl[1][j]=q1; ghl[2][j]=q2; ghl[3][j]=q3;
  }
  __syncthreads();
  // ---- gates combine: 512 = 4 rows x 128 h exactly ----
  {
    int r = t>>7, h = t&127;
    float ir_=gil[r][h], ii=gil[r][128+h], inw=gil[r][256+h];
    float hr_=ghl[r][h], hi2=ghl[r][128+h], hn=ghl[r][256+h];
    float rg=sigm(ir_+hr_), ig=sigm(ii+hi2), ng=tanhf(inw+rg*hn);
    float hv=h4[r][h];
    ws[dstOff + (g0+r)*128 + h] = ng + ig*(hv-ng);
  }
}

// ---- merged post-GRU: q2 (0..99) | qt->frags (100..199) | pad frags (200..247) | q1/ht/len (248..263) ----
__global__ void __launch_bounds__(256) k_post(const int* __restrict__ mask,
                      const float* __restrict__ b_two, const float* __restrict__ b_one,
                      float* __restrict__ ws){
  int bx = blockIdx.x, t = threadIdx.x;
  u16* qtbf = (u16*)(ws + OFF_QTBF);
  if (bx < 200){
    bool isq2 = bx < 100;
    int r0 = (isq2 ? bx : bx-100) * 8;
    __shared__ float hl[1024];
    for (int i=0;i<4;i++) hl[t+i*256] = ws[OFF_HID + r0*128 + t + i*256];
    __syncthreads();
    int h = t & 127, g = t >> 7;
    const float* wT = ws + (isq2 ? OFF_WTWOT : OFF_WTT);
    float binit = isq2 ? b_two[h] : 0.0f;
    float acc[4];
    #pragma unroll
    for (int r=0;r<4;r++) acc[r] = binit;
    for (int k4=0;k4<32;k4++){
      int k = k4*4;
      float w0 = wT[(k+0)*128+h], w1 = wT[(k+1)*128+h];
      float w2 = wT[(k+2)*128+h], w3 = wT[(k+3)*128+h];
      #pragma unroll
      for (int r=0;r<4;r++){
        float4 hv = *(const float4*)(hl + (g*4+r)*128 + k);
        acc[r] += hv.x*w0 + hv.y*w1 + hv.z*w2 + hv.w*w3;
      }
    }
    #pragma unroll
    for (int r=0;r<4;r++){
      int row = r0 + g*4 + r;
      if (isq2) ws[OFF_Q2 + row*128 + h] = acc[r];
      else {
        float val = mask[row] ? acc[r] : 0.0f;
        int b = row/NN, n = row - b*NN;
        qtbf[frag_idx(b, n, h)] = f2b(val);
      }
    }
  } else if (bx < 248){
    int i = (bx-200)*256 + t;
    #pragma unroll
    for (int kk=0;kk<2;kk++){
      int e = i*2 + kk;
      int b = e/1536, rem = e - b*1536;
      int kc = rem/384, rem2 = rem - kc*384;
      int quad = rem2/96, vv = rem2 - quad*96;
      int vlo = 4 + vv/8, j = vv & 7;
      qtbf[(((b*4+3)*4+kc)<<9) + ((quad<<4)+vlo)*8 + j] = 0;
    }
  } else {
    __shared__ float htl[128];
    int b = bx - 248;
    if (t < 128){
      int len = 0;
      for (int n=0;n<NN;n++) len += mask[b*NN+n];
      if (len<1) len=1; if (len>NN) len=NN;
      float ht = ws[OFF_HID + (b*NN + len-1)*128 + t];
      ws[OFF_HT + b*128 + t] = ht;
      htl[t] = ht;
      if (t==0) ((int*)(ws+OFF_LEN))[b] = len;
    }
    __syncthreads();
    if (t < 128){
      const float* w1T = ws + OFF_WONET;
      float q1 = b_one[t];
      for (int k=0;k<128;k+=4){
        float4 h4v = *(const float4*)(htl + k);
        q1 += h4v.x*w1T[(k+0)*128+t] + h4v.y*w1T[(k+1)*128+t]
            + h4v.z*w1T[(k+2)*128+t] + h4v.w*w1T[(k+3)*128+t];
      }
      ws[OFF_Q1 + b*128 + t] = q1;
    }
  }
}

// ---- attention: parallel logits + wave softmax + a + af; af -> frag rows 50/51 ----
__global__ void __launch_bounds__(256) k_attn2(const float* __restrict__ w_three,
                        const float* __restrict__ b_tr, float* __restrict__ ws){
  __shared__ float q2l[NN*129];
  __shared__ float q1l[128], w3l[128], htl[128], al[128], pt2[128], alg[64];
  int t = threadIdx.x;   // 256
  int b = blockIdx.x;
  for (int o=t;o<6400;o+=256){ int n=o>>7, h=o&127; q2l[n*129+h] = ws[OFF_Q2 + b*6400 + o]; }
  if (t < 128){
    q1l[t] = ws[OFF_Q1 + b*128 + t];
    w3l[t] = w_three[t];
    htl[t] = ws[OFF_HT + b*128 + t];
  }
  int len = ((const int*)(ws+OFF_LEN))[b];
  __syncthreads();
  if (t < 200){
    int n = t>>2, part = t&3;
    if (n < len){
      const float* qr  = q2l + n*129 + part*32;
      const float* q1p = q1l + part*32;
      const float* w3p = w3l + part*32;
      float s = 0.0f;
      for (int h=0;h<32;h++) s += w3p[h]*sigm(q1p[h]+qr[h]);
      s += __shfl_xor(s,1); s += __shfl_xor(s,2);
      if (part==0) alg[n] = s;
    }
  }
  __syncthreads();
  if (t < 64){
    float v = (t<len) ? alg[t] : -1e30f;
    float m = v;
    m = fmaxf(m, __shfl_xor(m,1));  m = fmaxf(m, __shfl_xor(m,2));
    m = fmaxf(m, __shfl_xor(m,4));  m = fmaxf(m, __shfl_xor(m,8));
    m = fmaxf(m, __shfl_xor(m,16)); m = fmaxf(m, __shfl_xor(m,32));
    float e = (t<len) ? __expf(v - m) : 0.0f;
    float ss = e;
    ss += __shfl_xor(ss,1);  ss += __shfl_xor(ss,2);
    ss += __shfl_xor(ss,4);  ss += __shfl_xor(ss,8);
    ss += __shfl_xor(ss,16); ss += __shfl_xor(ss,32);
    float inv = 1.0f/ss;
    if (t<len) alg[t] = e*inv;
  }
  __syncthreads();
  if (t < 128){
    const float* hid = ws + OFF_HID + b*6400;
    float a = 0.0f;
    for (int n=0;n<len;n++) a += alg[n]*hid[n*128+t];
    al[t] = a;
  }
  __syncthreads();
  float p1 = 0.0f;
  if (t < 256){
    int g2 = t>>7, h = t&127;
    const float* wtr = ws + OFF_WTRT + g2*128*128;
    const float* src = g2 ? htl : al;
    float p = 0.0f;
    for (int k=0;k<128;k++) p += src[k]*wtr[k*128+h];
    if (g2) pt2[h] = p; else p1 = p;
  }
  __syncthreads();
  if (t < 128){
    float af = b_tr[t] + p1 + pt2[t];
    u16 hi = f2b(af);
    u16 lo = f2b(af - b2f(hi));
    u16* qtbf = (u16*)(ws + OFF_QTBF);
    qtbf[frag_idx(b, 50, t)] = hi;
    qtbf[frag_idx(b, 51, t)] = lo;
  }
}

// ---- MFMA scores: LDS-staged fragments; grid (4,625): x=b-group (L2 emb reuse), y=v-chunk ----
__global__ void __launch_bounds__(256) k_scores(const float* __restrict__ emb,
                                                const float* __restrict__ ws,
                                                float* __restrict__ out){
  __shared__ u16 qlds[8192];   // 16 KB = one b's fragment block
  int tid = threadIdx.x;
  int lane = tid & 63, wave = tid >> 6;
  int quad = lane >> 4, vlo = lane & 15;
  int v = blockIdx.y*64 + wave*16 + vlo;
  int vc = (v < VO) ? v : (VO-1);
  const float* erow = emb + (size_t)(vc+1)*128;
  short8 bfr[4];
  #pragma unroll
  for (int kc=0;kc<4;kc++){
    const float4* p = (const float4*)(erow + kc*32 + quad*8);
    float4 x = p[0], y = p[1];
    union { short8 s; u32 w[4]; } u;
    u.w[0] = (u32)f2b(x.x) | ((u32)f2b(x.y)<<16);
    u.w[1] = (u32)f2b(x.z) | ((u32)f2b(x.w)<<16);
    u.w[2] = (u32)f2b(y.x) | ((u32)f2b(y.y)<<16);
    u.w[3] = (u32)f2b(y.z) | ((u32)f2b(y.w)<<16);
    bfr[kc] = u.s;
  }
  const u16* qtf = (const u16*)(ws + OFF_QTBF);
  const int* slen = (const int*)(ws + OFF_LEN);
  int b0 = blockIdx.x*4;
  for (int bi=0;bi<4;bi++){
    int b = b0 + bi;
    __syncthreads();
    {
      const uint4* src = (const uint4*)qtf + (size_t)b*1024;
      uint4* dst = (uint4*)qlds;
      #pragma unroll
      for (int r=0;r<4;r++) dst[tid + r*256] = src[tid + r*256];
    }
    __syncthreads();
    int len = slen[b];
    f32x4 acc0={0.f,0.f,0.f,0.f}, acc1=acc0, acc2=acc0, acc3=acc0;
    #pragma unroll
    for (int kc=0;kc<4;kc++){
      const u16* base = qlds + kc*512 + lane*8;   // tile stride 2048 u16
      short8 a0 = *(const short8*)(base + 0*2048);
      short8 a1 = *(const short8*)(base + 1*2048);
      short8 a2 = *(const short8*)(base + 2*2048);
      short8 a3 = *(const short8*)(base + 3*2048);
      acc0 = __builtin_amdgcn_mfma_f32_16x16x32_bf16(a0, bfr[kc], acc0, 0,0,0);
      acc1 = __builtin_amdgcn_mfma_f32_16x16x32_bf16(a1, bfr[kc], acc1, 0,0,0);
      acc2 = __builtin_amdgcn_mfma_f32_16x16x32_bf16(a2, bfr[kc], acc2, 0,0,0);
      acc3 = __builtin_amdgcn_mfma_f32_16x16x32_bf16(a3, bfr[kc], acc3, 0,0,0);
    }
    int nb = quad*4;
    float ss=0.f, nm=0.f;
    #pragma unroll
    for (int r=0;r<4;r++){
      { int n=nb+r;    if(n<len){ float e=__expf(acc0[r]); ss+=e; nm+=e*acc0[r]; } }
      { int n=nb+r+16; if(n<len){ float e=__expf(acc1[r]); ss+=e; nm+=e*acc1[r]; } }
      { int n=nb+r+32; if(n<len){ float e=__expf(acc2[r]); ss+=e; nm+=e*acc2[r]; } }
      { int n=nb+r+48; if(n<len){ float e=__expf(acc3[r]); ss+=e; nm+=e*acc3[r]; } }
    }
    ss += __shfl_xor(ss,16); ss += __shfl_xor(ss,32);
    nm += __shfl_xor(nm,16); nm += __shfl_xor(nm,32);
    if (quad==0 && v < VO){
      float pa = acc3[2] + acc3[3];   // n=50 (af_hi) + n=51 (af_lo)
      out[(size_t)b*VO + v] = nm/ss + pa;
    }
  }
}

extern "C" void kernel_launch(void* const* d_in, const int* in_sizes, int n_in,
                              void* d_out, int out_size, void* d_ws, size_t ws_size,
                              hipStream_t stream){
  const int*   items  = (const int*)d_in[0];
  const float* A      = (const float*)d_in[1];
  const int*   mask   = (const int*)d_in[2];
  const float* emb    = (const float*)d_in[3];
  const float* w_ih   = (const float*)d_in[4];
  const float* w_hh   = (const float*)d_in[5];
  const float* b_ih   = (const float*)d_in[6];
  const float* b_hh   = (const float*)d_in[7];
  const float* b_iah  = (const float*)d_in[8];
  const float* b_oah  = (const float*)d_in[9];
  const float* W_ein  = (const float*)d_in[10];
  const float* b_ein  = (const float*)d_in[11];
  const float* W_eout = (const float*)d_in[12];
  const float* b_eout = (const float*)d_in[13];
  const float* W_one  = (const float*)d_in[14];
  const float* b_one  = (const float*)d_in[15];
  const float* W_two  = (const float*)d_in[16];
  const float* b_two  = (const float*)d_in[17];
  const float* w_three= (const float*)d_in[18];
  const float* W_tr   = (const float*)d_in[19];
  const float* b_tr   = (const float*)d_in[20];
  const float* W_t    = (const float*)d_in[21];
  float* ws  = (float*)d_ws;
  float* out = (float*)d_out;

  k_pre<<<1040,256,0,stream>>>(items,emb,W_two,W_t,W_one,W_tr,W_ein,W_eout,w_hh,ws);
  k_ha   <<<dim3(13,16),384,0,stream>>>(A,ws,OFF_HID);
  k_gates<<<200,512,0,stream>>>(w_ih,b_ein,b_eout,b_iah,b_oah,b_ih,b_hh,ws,OFF_HID,OFF_HID2);
  k_ha   <<<dim3(13,16),384,0,stream>>>(A,ws,OFF_HID2);
  k_gates<<<200,512,0,stream>>>(w_ih,b_ein,b_eout,b_iah,b_oah,b_ih,b_hh,ws,OFF_HID2,OFF_HID);
  k_post <<<264,256,0,stream>>>(mask,b_two,b_one,ws);
  k_attn2<<<16,256,0,stream>>>(w_three,b_tr,ws);
  k_scores<<<dim3(4,625),256,0,stream>>>(emb,ws,out);
}

// Round 9
// 209.719 us; speedup vs baseline: 1.2486x; 1.0439x over previous
//
#include <hip/hip_runtime.h>

#define BB 16
#define NN 50
#define HH 128
#define VV 40000
#define VO 39999

typedef unsigned short u16;
typedef unsigned int u32;
typedef __attribute__((ext_vector_type(8))) short short8;
typedef __attribute__((ext_vector_type(4))) float f32x4;

// ---- workspace layout (float offsets) ----
#define OFF_HID    0          // 800*128
#define OFF_HID2   102400     // 800*128 (GRU double buffer; reused as Q2 after GRU)
#define OFF_Q2     102400
#define OFF_Q1     204800     // 16*128
#define OFF_HT     206848     // 16*128
#define OFF_WTWOT  208896     // 128*128 k-major
#define OFF_WTT    225280
#define OFF_WONET  241664
#define OFF_WTRT   258048     // 256*128 -> 290816
#define OFF_WEINT  290816     // 128*128 k-major -> 307200
#define OFF_QTBF   307200     // qt frags: 16 b x 8192 u16 = 65536 f32 -> 372736
#define OFF_WEOUTT 372736     // 128*128 k-major -> 389120
#define OFF_LEN    411648     // 16 ints
#define OFF_WHHT   616464     // 128*384 k-major -> 665616

__device__ __forceinline__ float sigm(float x){ return 1.0f/(1.0f+__expf(-x)); }
__device__ __forceinline__ float b2f(u16 u){
  union { u32 i; float f; } c; c.i = ((u32)u) << 16; return c.f;
}
__device__ __forceinline__ u16 f2b(float f){
  union { float f; u32 i; } c; c.f = f;
  u32 u = c.i;
  return (u16)((u + 0x7fffu + ((u >> 16) & 1u)) >> 16);
}
__device__ __forceinline__ int frag_idx(int b, int n, int k){
  int tile = n>>4, vlo = n&15, kc = k>>5, quad = (k>>3)&3, j = k&7;
  return (((b*4+tile)*4+kc)<<9) + ((quad<<4)+vlo)*8 + j;
}

// ---- merged: embedding gather + k-major transposes ----
__global__ void k_pre(const int* __restrict__ items, const float* __restrict__ emb,
                      const float* __restrict__ W_two, const float* __restrict__ W_t,
                      const float* __restrict__ W_one, const float* __restrict__ W_tr,
                      const float* __restrict__ W_ein, const float* __restrict__ W_eout,
                      const float* __restrict__ w_hh, float* __restrict__ ws){
  int idx = blockIdx.x*256 + threadIdx.x;     // grid covers exactly 266240
  if (idx < 102400){
    int r = idx >> 7, h = idx & 127;
    ws[OFF_HID + idx] = emb[items[r]*128 + h];
  } else if (idx < 118784){
    int i = idx-102400; int k=i>>7, h=i&127;
    ws[OFF_WTWOT + i] = W_two[h*128 + k];
  } else if (idx < 135168){
    int i = idx-118784; int k=i>>7, h=i&127;
    ws[OFF_WTT + i] = W_t[h*128 + k];
  } else if (idx < 151552){
    int i = idx-135168; int k=i>>7, h=i&127;
    ws[OFF_WONET + i] = W_one[h*128 + k];
  } else if (idx < 184320){
    int i = idx-151552; int k=i>>7, h=i&127;   // k<256
    ws[OFF_WTRT + i] = W_tr[h*256 + k];
  } else if (idx < 200704){
    int i = idx-184320; int k=i>>7, h=i&127;
    ws[OFF_WEINT + i] = W_ein[h*128 + k];
  } else if (idx < 217088){
    int i = idx-200704; int k=i>>7, h=i&127;
    ws[OFF_WEOUTT + i] = W_eout[h*128 + k];
  } else if (idx < 266240){
    int i = idx-217088; int k=i/384, j=i-k*384;   // k<128, j<384
    ws[OFF_WHHT + i] = w_hh[j*128 + k];
  }
}

// ---- merged GRU step: hall->hA->inp->gates in one block; grid (13,16) x 512 ----
__global__ void __launch_bounds__(512) k_step2(const float* __restrict__ A,
                       const float* __restrict__ w_ih,
                       const float* __restrict__ b_ein, const float* __restrict__ b_eout,
                       const float* __restrict__ b_iah, const float* __restrict__ b_oah,
                       const float* __restrict__ b_ih, const float* __restrict__ b_hh,
                       float* __restrict__ ws, int srcOff, int dstOff){
  __shared__ float hall[50][128];    // 25.6 KB
  __shared__ float arow[4][104];     // 1.7 KB
  __shared__ float ha4[4][256];      // 4 KB
  __shared__ float sa4[4][2];
  __shared__ float inp4[4][256];     // 4 KB
  __shared__ float gil[4][384];      // 6 KB
  __shared__ float ghl[4][384];      // 6 KB
  __shared__ float wtile[16][385];   // 24.6 KB (padded: conflict-free stage+read)
  int t = threadIdx.x;
  int tile = blockIdx.x, b = blockIdx.y;
  int n0 = tile*4;
  const float* hsrc = ws + srcOff + b*6400;
  for (int o=t; o<1600; o+=512) ((float4*)hall)[o] = ((const float4*)hsrc)[o];
  if (t < 416){
    int r=t/104, c=t-r*104;
    arow[r][c] = (c<100 && n0+r<NN) ? A[(size_t)(b*NN+n0+r)*100 + c] : 0.0f;
  }
  __syncthreads();
  // ---- hA[r][kk]: kk<128 from A cols 0..49 (in), kk>=128 from cols 50..99 (out) ----
  for (int o=t; o<1024; o+=512){
    int r = o>>8, kk = o&255;
    int k = kk & 127;
    const float* ar = &arow[r][(kk>>7)*50];
    float acc = 0.0f;
    #pragma unroll 5
    for (int m=0;m<50;m++) acc += ar[m]*hall[m][k];
    ha4[r][kk] = acc;
  }
  if (t < 8){
    int r = t>>1, half = t&1;
    const float* ar = &arow[r][half*50];
    float s = 0.0f;
    for (int m=0;m<50;m++) s += ar[m];
    sa4[r][half] = s;
  }
  __syncthreads();
  // ---- inp = hA@WeT + bias folds (K=128, k-major coalesced) ----
  {
    int c8 = t & 255, rb = t >> 8;   // rb in {0,1}: rows rb and rb+2
    int in_half = (c8 < 128) ? 1 : 0;
    int c = c8 & 127;
    const float* wT = ws + (in_half ? OFF_WEINT : OFF_WEOUTT) + c;
    const float* haA = &ha4[rb][in_half ? 0 : 128];
    const float* haB = &ha4[rb+2][in_half ? 0 : 128];
    float a0 = in_half ? (b_iah[c] + sa4[rb  ][0]*b_ein[c]) : (b_oah[c] + sa4[rb  ][1]*b_eout[c]);
    float a1 = in_half ? (b_iah[c] + sa4[rb+2][0]*b_ein[c]) : (b_oah[c] + sa4[rb+2][1]*b_eout[c]);
    for (int k=0;k<128;k+=4){
      float w0=wT[(k+0)*128], w1=wT[(k+1)*128], w2=wT[(k+2)*128], w3=wT[(k+3)*128];
      float4 hA = *(const float4*)(haA + k);
      float4 hB = *(const float4*)(haB + k);
      a0 += hA.x*w0 + hA.y*w1 + hA.z*w2 + hA.w*w3;
      a1 += hB.x*w0 + hB.y*w1 + hB.z*w2 + hB.w*w3;
    }
    inp4[rb][c8] = a0;
    inp4[rb+2][c8] = a1;
  }
  __syncthreads();
  // ---- gi = inp@w_ih^T (K=256): 16-wide K-chunks, w_ih coop-staged+transposed ----
  int j = t;
  float gacc0=0,gacc1=0,gacc2=0,gacc3=0;
  if (j < 384){ float bi = b_ih[j]; gacc0=gacc1=gacc2=gacc3=bi; }
  for (int k0=0;k0<256;k0+=16){
    #pragma unroll
    for (int q=0;q<3;q++){
      int u = t + q*512;               // 1536 float4 loads, 64B granules
      int row = u>>2, seg = u&3;
      float4 v = *(const float4*)(w_ih + row*256 + k0 + seg*4);
      int kb = seg*4;
      wtile[kb+0][row]=v.x; wtile[kb+1][row]=v.y; wtile[kb+2][row]=v.z; wtile[kb+3][row]=v.w;
    }
    __syncthreads();
    if (j < 384){
      #pragma unroll
      for (int kk=0;kk<16;kk++){
        float w = wtile[kk][j];
        gacc0 += w*inp4[0][k0+kk];
        gacc1 += w*inp4[1][k0+kk];
        gacc2 += w*inp4[2][k0+kk];
        gacc3 += w*inp4[3][k0+kk];
      }
    }
    __syncthreads();
  }
  if (j < 384){ gil[0][j]=gacc0; gil[1][j]=gacc1; gil[2][j]=gacc2; gil[3][j]=gacc3; }
  // ---- gh = H@w_hh^T (K=128, k-major coalesced) ----
  if (j < 384){
    float bh = b_hh[j];
    float q0=bh,q1=bh,q2=bh,q3=bh;
    const float* wT = ws + OFF_WHHT + j;
    int r1 = (n0+1<NN)? n0+1 : n0;
    int r2 = (n0+2<NN)? n0+2 : n0;
    int r3 = (n0+3<NN)? n0+3 : n0;
    for (int k=0;k<128;k+=4){
      float w0=wT[(k+0)*384], w1=wT[(k+1)*384], w2=wT[(k+2)*384], w3=wT[(k+3)*384];
      float4 v0 = *(const float4*)(&hall[n0][k]);
      float4 v1 = *(const float4*)(&hall[r1][k]);
      float4 v2 = *(const float4*)(&hall[r2][k]);
      float4 v3 = *(const float4*)(&hall[r3][k]);
      q0 += v0.x*w0 + v0.y*w1 + v0.z*w2 + v0.w*w3;
      q1 += v1.x*w0 + v1.y*w1 + v1.z*w2 + v1.w*w3;
      q2 += v2.x*w0 + v2.y*w1 + v2.z*w2 + v2.w*w3;
      q3 += v3.x*w0 + v3.y*w1 + v3.z*w2 + v3.w*w3;
    }
    ghl[0][j]=q0; ghl[1][j]=q1; ghl[2][j]=q2; ghl[3][j]=q3;
  }
  __syncthreads();
  // ---- gates combine: 512 = 4 rows x 128 h ----
  {
    int r = t>>7, h = t&127, row = n0+r;
    if (row < NN){
      float ir_=gil[r][h], ii=gil[r][128+h], inw=gil[r][256+h];
      float hr_=ghl[r][h], hi2=ghl[r][128+h], hn=ghl[r][256+h];
      float rg=sigm(ir_+hr_), ig=sigm(ii+hi2), ng=tanhf(inw+rg*hn);
      float hv=hall[row][h];
      ws[dstOff + (b*NN+row)*128 + h] = ng + ig*(hv-ng);
    }
  }
}

// ---- merged post-GRU: q2 (0..99) | qt->frags (100..199) | pad frags (200..247) | q1/ht/len (248..263) ----
__global__ void __launch_bounds__(256) k_post(const int* __restrict__ mask,
                      const float* __restrict__ b_two, const float* __restrict__ b_one,
                      float* __restrict__ ws){
  int bx = blockIdx.x, t = threadIdx.x;
  u16* qtbf = (u16*)(ws + OFF_QTBF);
  if (bx < 200){
    bool isq2 = bx < 100;
    int r0 = (isq2 ? bx : bx-100) * 8;
    __shared__ float hl[1024];
    for (int i=0;i<4;i++) hl[t+i*256] = ws[OFF_HID + r0*128 + t + i*256];
    __syncthreads();
    int h = t & 127, g = t >> 7;
    const float* wT = ws + (isq2 ? OFF_WTWOT : OFF_WTT);
    float binit = isq2 ? b_two[h] : 0.0f;
    float acc[4];
    #pragma unroll
    for (int r=0;r<4;r++) acc[r] = binit;
    for (int k4=0;k4<32;k4++){
      int k = k4*4;
      float w0 = wT[(k+0)*128+h], w1 = wT[(k+1)*128+h];
      float w2 = wT[(k+2)*128+h], w3 = wT[(k+3)*128+h];
      #pragma unroll
      for (int r=0;r<4;r++){
        float4 hv = *(const float4*)(hl + (g*4+r)*128 + k);
        acc[r] += hv.x*w0 + hv.y*w1 + hv.z*w2 + hv.w*w3;
      }
    }
    #pragma unroll
    for (int r=0;r<4;r++){
      int row = r0 + g*4 + r;
      if (isq2) ws[OFF_Q2 + row*128 + h] = acc[r];
      else {
        float val = mask[row] ? acc[r] : 0.0f;
        int b = row/NN, n = row - b*NN;
        qtbf[frag_idx(b, n, h)] = f2b(val);
      }
    }
  } else if (bx < 248){
    int i = (bx-200)*256 + t;
    #pragma unroll
    for (int kk=0;kk<2;kk++){
      int e = i*2 + kk;
      int b = e/1536, rem = e - b*1536;
      int kc = rem/384, rem2 = rem - kc*384;
      int quad = rem2/96, vv = rem2 - quad*96;
      int vlo = 4 + vv/8, j = vv & 7;
      qtbf[(((b*4+3)*4+kc)<<9) + ((quad<<4)+vlo)*8 + j] = 0;
    }
  } else {
    __shared__ float htl[128];
    int b = bx - 248;
    if (t < 128){
      int len = 0;
      for (int n=0;n<NN;n++) len += mask[b*NN+n];
      if (len<1) len=1; if (len>NN) len=NN;
      float ht = ws[OFF_HID + (b*NN + len-1)*128 + t];
      ws[OFF_HT + b*128 + t] = ht;
      htl[t] = ht;
      if (t==0) ((int*)(ws+OFF_LEN))[b] = len;
    }
    __syncthreads();
    if (t < 128){
      const float* w1T = ws + OFF_WONET;
      float q1 = b_one[t];
      for (int k=0;k<128;k+=4){
        float4 h4v = *(const float4*)(htl + k);
        q1 += h4v.x*w1T[(k+0)*128+t] + h4v.y*w1T[(k+1)*128+t]
            + h4v.z*w1T[(k+2)*128+t] + h4v.w*w1T[(k+3)*128+t];
      }
      ws[OFF_Q1 + b*128 + t] = q1;
    }
  }
}

// ---- attention: parallel logits + wave softmax + a + af; af -> frag rows 50/51 ----
__global__ void __launch_bounds__(256) k_attn2(const float* __restrict__ w_three,
                        const float* __restrict__ b_tr, float* __restrict__ ws){
  __shared__ float q2l[NN*129];
  __shared__ float q1l[128], w3l[128], htl[128], al[128], pt2[128], alg[64];
  int t = threadIdx.x;   // 256
  int b = blockIdx.x;
  for (int o=t;o<6400;o+=256){ int n=o>>7, h=o&127; q2l[n*129+h] = ws[OFF_Q2 + b*6400 + o]; }
  if (t < 128){
    q1l[t] = ws[OFF_Q1 + b*128 + t];
    w3l[t] = w_three[t];
    htl[t] = ws[OFF_HT + b*128 + t];
  }
  int len = ((const int*)(ws+OFF_LEN))[b];
  __syncthreads();
  if (t < 200){
    int n = t>>2, part = t&3;
    if (n < len){
      const float* qr  = q2l + n*129 + part*32;
      const float* q1p = q1l + part*32;
      const float* w3p = w3l + part*32;
      float s = 0.0f;
      for (int h=0;h<32;h++) s += w3p[h]*sigm(q1p[h]+qr[h]);
      s += __shfl_xor(s,1); s += __shfl_xor(s,2);
      if (part==0) alg[n] = s;
    }
  }
  __syncthreads();
  if (t < 64){
    float v = (t<len) ? alg[t] : -1e30f;
    float m = v;
    m = fmaxf(m, __shfl_xor(m,1));  m = fmaxf(m, __shfl_xor(m,2));
    m = fmaxf(m, __shfl_xor(m,4));  m = fmaxf(m, __shfl_xor(m,8));
    m = fmaxf(m, __shfl_xor(m,16)); m = fmaxf(m, __shfl_xor(m,32));
    float e = (t<len) ? __expf(v - m) : 0.0f;
    float ss = e;
    ss += __shfl_xor(ss,1);  ss += __shfl_xor(ss,2);
    ss += __shfl_xor(ss,4);  ss += __shfl_xor(ss,8);
    ss += __shfl_xor(ss,16); ss += __shfl_xor(ss,32);
    float inv = 1.0f/ss;
    if (t<len) alg[t] = e*inv;
  }
  __syncthreads();
  if (t < 128){
    const float* hid = ws + OFF_HID + b*6400;
    float a = 0.0f;
    for (int n=0;n<len;n++) a += alg[n]*hid[n*128+t];
    al[t] = a;
  }
  __syncthreads();
  float p1 = 0.0f;
  if (t < 256){
    int g2 = t>>7, h = t&127;
    const float* wtr = ws + OFF_WTRT + g2*128*128;
    const float* src = g2 ? htl : al;
    float p = 0.0f;
    for (int k=0;k<128;k++) p += src[k]*wtr[k*128+h];
    if (g2) pt2[h] = p; else p1 = p;
  }
  __syncthreads();
  if (t < 128){
    float af = b_tr[t] + p1 + pt2[t];
    u16 hi = f2b(af);
    u16 lo = f2b(af - b2f(hi));
    u16* qtbf = (u16*)(ws + OFF_QTBF);
    qtbf[frag_idx(b, 50, t)] = hi;
    qtbf[frag_idx(b, 51, t)] = lo;
  }
}

// ---- MFMA scores: LDS-staged fragments; grid (4,625): x=b-group (L2 emb reuse), y=v-chunk ----
__global__ void __launch_bounds__(256) k_scores(const float* __restrict__ emb,
                                                const float* __restrict__ ws,
                                                float* __restrict__ out){
  __shared__ u16 qlds[8192];   // 16 KB = one b's fragment block
  int tid = threadIdx.x;
  int lane = tid & 63, wave = tid >> 6;
  int quad = lane >> 4, vlo = lane & 15;
  int v = blockIdx.y*64 + wave*16 + vlo;
  int vc = (v < VO) ? v : (VO-1);
  const float* erow = emb + (size_t)(vc+1)*128;
  short8 bfr[4];
  #pragma unroll
  for (int kc=0;kc<4;kc++){
    const float4* p = (const float4*)(erow + kc*32 + quad*8);
    float4 x = p[0], y = p[1];
    union { short8 s; u32 w[4]; } u;
    u.w[0] = (u32)f2b(x.x) | ((u32)f2b(x.y)<<16);
    u.w[1] = (u32)f2b(x.z) | ((u32)f2b(x.w)<<16);
    u.w[2] = (u32)f2b(y.x) | ((u32)f2b(y.y)<<16);
    u.w[3] = (u32)f2b(y.z) | ((u32)f2b(y.w)<<16);
    bfr[kc] = u.s;
  }
  const u16* qtf = (const u16*)(ws + OFF_QTBF);
  const int* slen = (const int*)(ws + OFF_LEN);
  int b0 = blockIdx.x*4;
  for (int bi=0;bi<4;bi++){
    int b = b0 + bi;
    __syncthreads();
    {
      const uint4* src = (const uint4*)qtf + (size_t)b*1024;
      uint4* dst = (uint4*)qlds;
      #pragma unroll
      for (int r=0;r<4;r++) dst[tid + r*256] = src[tid + r*256];
    }
    __syncthreads();
    int len = slen[b];
    f32x4 acc0={0.f,0.f,0.f,0.f}, acc1=acc0, acc2=acc0, acc3=acc0;
    #pragma unroll
    for (int kc=0;kc<4;kc++){
      const u16* base = qlds + kc*512 + lane*8;   // tile stride 2048 u16
      short8 a0 = *(const short8*)(base + 0*2048);
      short8 a1 = *(const short8*)(base + 1*2048);
      short8 a2 = *(const short8*)(base + 2*2048);
      short8 a3 = *(const short8*)(base + 3*2048);
      acc0 = __builtin_amdgcn_mfma_f32_16x16x32_bf16(a0, bfr[kc], acc0, 0,0,0);
      acc1 = __builtin_amdgcn_mfma_f32_16x16x32_bf16(a1, bfr[kc], acc1, 0,0,0);
      acc2 = __builtin_amdgcn_mfma_f32_16x16x32_bf16(a2, bfr[kc], acc2, 0,0,0);
      acc3 = __builtin_amdgcn_mfma_f32_16x16x32_bf16(a3, bfr[kc], acc3, 0,0,0);
    }
    int nb = quad*4;
    float ss=0.f, nm=0.f;
    #pragma unroll
    for (int r=0;r<4;r++){
      { int n=nb+r;    if(n<len){ float e=__expf(acc0[r]); ss+=e; nm+=e*acc0[r]; } }
      { int n=nb+r+16; if(n<len){ float e=__expf(acc1[r]); ss+=e; nm+=e*acc1[r]; } }
      { int n=nb+r+32; if(n<len){ float e=__expf(acc2[r]); ss+=e; nm+=e*acc2[r]; } }
      { int n=nb+r+48; if(n<len){ float e=__expf(acc3[r]); ss+=e; nm+=e*acc3[r]; } }
    }
    ss += __shfl_xor(ss,16); ss += __shfl_xor(ss,32);
    nm += __shfl_xor(nm,16); nm += __shfl_xor(nm,32);
    if (quad==0 && v < VO){
      float pa = acc3[2] + acc3[3];   // n=50 (af_hi) + n=51 (af_lo)
      out[(size_t)b*VO + v] = nm/ss + pa;
    }
  }
}

extern "C" void kernel_launch(void* const* d_in, const int* in_sizes, int n_in,
                              void* d_out, int out_size, void* d_ws, size_t ws_size,
                              hipStream_t stream){
  const int*   items  = (const int*)d_in[0];
  const float* A      = (const float*)d_in[1];
  const int*   mask   = (const int*)d_in[2];
  const float* emb    = (const float*)d_in[3];
  const float* w_ih   = (const float*)d_in[4];
  const float* w_hh   = (const float*)d_in[5];
  const float* b_ih   = (const float*)d_in[6];
  const float* b_hh   = (const float*)d_in[7];
  const float* b_iah  = (const float*)d_in[8];
  const float* b_oah  = (const float*)d_in[9];
  const float* W_ein  = (const float*)d_in[10];
  const float* b_ein  = (const float*)d_in[11];
  const float* W_eout = (const float*)d_in[12];
  const float* b_eout = (const float*)d_in[13];
  const float* W_one  = (const float*)d_in[14];
  const float* b_one  = (const float*)d_in[15];
  const float* W_two  = (const float*)d_in[16];
  const float* b_two  = (const float*)d_in[17];
  const float* w_three= (const float*)d_in[18];
  const float* W_tr   = (const float*)d_in[19];
  const float* b_tr   = (const float*)d_in[20];
  const float* W_t    = (const float*)d_in[21];
  float* ws  = (float*)d_ws;
  float* out = (float*)d_out;

  k_pre<<<1040,256,0,stream>>>(items,emb,W_two,W_t,W_one,W_tr,W_ein,W_eout,w_hh,ws);
  k_step2<<<dim3(13,16),512,0,stream>>>(A,w_ih,b_ein,b_eout,b_iah,b_oah,b_ih,b_hh,ws,OFF_HID,OFF_HID2);
  k_step2<<<dim3(13,16),512,0,stream>>>(A,w_ih,b_ein,b_eout,b_iah,b_oah,b_ih,b_hh,ws,OFF_HID2,OFF_HID);
  k_post <<<264,256,0,stream>>>(mask,b_two,b_one,ws);
  k_attn2<<<16,256,0,stream>>>(w_three,b_tr,ws);
  k_scores<<<dim3(4,625),256,0,stream>>>(emb,ws,out);
}